// Round 8
// baseline (3011.888 us; speedup 1.0000x reference)
//
#include <hip/hip_runtime.h>
#include <hip/hip_bf16.h>
#include <cstdint>

// GraphSAGE 2-layer, bf16 features + fp32 accumulate, MFMA GEMMs.
// Layer1: h   = relu([mean_agg(x) | x] @ [W1_l; W1_r] + b1)   (K=256 MFMA GEMM)
// Layer2: out = mean_agg(h @ W2_l) + h @ W2_r + b2            (agg commutes w/ linear)
// R18 pipeline (5 dispatches):
//   memset(bucket_pos+ucnt) -> fused_front (pass2 sorted-partition|cvt|wfrags)
//   -> pass3 -> agg128_gemm (MERGED: agg + last-finisher gemm overlap)
//   -> agg64 (dual-node, epilogue reads out in-place)
// R18: agg128 and gemm12 overlap INTRA-KERNEL. Merged grid = 25000 agg blocks
// (agg structure IDENTICAL to the proven 59us kernel). After storing its 4
// meanb rows each block: syncthreads (drains stores) -> thread0 threadfence
// (agent release, wbl2) + atomicAdd(ucnt[unit]) ; last finisher of each
// 64-row unit (16 blocks) acquires (threadfence) and runs that unit's gemm
// (R14 16-row/wave shape, single-buffer weights, ~90 VGPR @ (256,5)).
// Deadlock-free: no block ever waits on another. gemm's x-side output goes
// DIRECTLY to d_out (no xb aliasing -> no race with concurrent gathers);
// agg64 reads+writes out in place. gemm work spreads across agg's 59us
// shadow (different resources: L2 weight stream+MFMA vs L3-miss gather).
// LEDGER: agg128 59=floor(177.8MB@3.5TB/s); agg64 ~41 (R17 dual-node WIN
// -4.2us); front+pass3+gemm ~60-75 est; ~30 harness dispatches/iter fixed.
// R13 (mega-fusion) FALSIFIED: SERIAL per-bucket agg+gemm = 145us. R18
// differs: agg keeps full TLP; gemm is appended dynamically, not serialized.
// R14 (16row gemm standalone) FALSIFIED as replacement (+8.6us) but fine as
// overlap filler. R11/R10/R15 agg restructures FALSIFIED — do not revisit.
// NOTE: fdot2_f32_bf16 gave WRONG results on gfx950 (R6) — do not use.

typedef __bf16 bf16x8 __attribute__((ext_vector_type(8)));
typedef float f32x4 __attribute__((ext_vector_type(4)));
typedef float f32x2 __attribute__((ext_vector_type(2)));

#define MAXBUCK 800   // >= ceil(102400/128)
#define CAP 2560      // per-bucket edge capacity; mean 2046, sigma ~45
#define MAXEPT 16
#define P2B 512       // pass2 blocks
#define P2E (MAXEPT * 256)   // staging capacity (4096; ept=13 uses 3328)
#define HSTRIDE 136   // bf16 elems per scratch row (272B, 16B-aligned)

__device__ __forceinline__ unsigned short f2bf(float f) {
    union { float f; unsigned int u; } v; v.f = f;
    unsigned int u = v.u;
    unsigned int r = ((u >> 16) & 1u) + 0x7fffu;
    return (unsigned short)((u + r) >> 16);
}

// unpack uint (2 bf16) -> f32x2 {lo, hi}
__device__ __forceinline__ f32x2 up2(unsigned int u) {
    uint2 t; t.x = u << 16; t.y = u & 0xffff0000u;
    return __builtin_bit_cast(f32x2, t);
}
__device__ __forceinline__ void accp(const uint4& v, f32x2* a) {
    a[0] += up2(v.x);
    a[1] += up2(v.y);
    a[2] += up2(v.z);
    a[3] += up2(v.w);
}
__device__ __forceinline__ void accpw(const uint4& v, float w, f32x2* a) {
    a[0] += up2(v.x) * w;
    a[1] += up2(v.y) * w;
    a[2] += up2(v.z) * w;
    a[3] += up2(v.w) * w;
}

__device__ __forceinline__ int edge_val(const int* ei32, const long long* ei64,
                                        int is64, size_t idx) {
    return is64 ? (int)ei64[idx] : ei32[idx];
}

// ---------------- FUSED FRONT: pass2 sorted-partition | cvt | w frags ------
__global__ __launch_bounds__(256) void fused_front(const float* __restrict__ x,
                                                   unsigned short* __restrict__ xb,
                                                   long long n8, int ncvt,
                                                   const float* __restrict__ W1l,
                                                   const float* __restrict__ W1r,
                                                   uint4* __restrict__ w1frag,
                                                   const float* __restrict__ W2l,
                                                   const float* __restrict__ W2r,
                                                   uint4* __restrict__ w2frag,
                                                   const int* __restrict__ ei32,
                                                   const long long* __restrict__ ei64,
                                                   int E, int ept, int nbuck,
                                                   int n_nodes,
                                                   int* __restrict__ bucket_pos,
                                                   unsigned* __restrict__ ebuf) {
    __shared__ int lhist[MAXBUCK];
    __shared__ int lexcl[MAXBUCK];
    __shared__ int gbase[MAXBUCK];
    __shared__ int part[256];
    __shared__ unsigned estage[P2E];
    __shared__ unsigned short bstage[P2E];
    int b = blockIdx.x;
    int t = threadIdx.x;
    if (b < P2B) {
        // ---- pass2 role: partition edges into padded buckets, sorted ----
        for (int i = t; i < nbuck; i += 256) lhist[i] = 0;
        __syncthreads();
        int is64;
        {   // self-detect: 8 uniform loads; garbage-as-int64 fails bounds
            int ok = 1;
            for (int i = 0; i < 8; ++i) {
                long long v = ei64[i];
                if (v < 0 || v >= n_nodes) ok = 0;
            }
            is64 = ok;
        }
        int base_e = b * (ept * 256);
        unsigned ed[MAXEPT];
        int bidx[MAXEPT];
        int slot[MAXEPT];
#pragma unroll 4
        for (int i = 0; i < ept; ++i) {
            int e = base_e + i * 256 + t;
            if (e < E) {
                int s = edge_val(ei32, ei64, is64, (size_t)e);
                int d = edge_val(ei32, ei64, is64, (size_t)E + e);
                ed[i] = ((unsigned)s << 7) | (unsigned)(d & 127);
                bidx[i] = d >> 7;
                slot[i] = atomicAdd(&lhist[d >> 7], 1);
            } else {
                slot[i] = -1;
            }
        }
        __syncthreads();
        // block-local exclusive scan of lhist[0..nbuck) (4 buckets/thread)
        int base4 = t * 4;
        int c0 = (base4 + 0 < nbuck) ? lhist[base4 + 0] : 0;
        int c1 = (base4 + 1 < nbuck) ? lhist[base4 + 1] : 0;
        int c2 = (base4 + 2 < nbuck) ? lhist[base4 + 2] : 0;
        int c3 = (base4 + 3 < nbuck) ? lhist[base4 + 3] : 0;
        int lsum = c0 + c1 + c2 + c3;
        part[t] = lsum;
        __syncthreads();
        for (int o = 1; o < 256; o <<= 1) {
            int xv = 0;
            if (t >= o) xv = part[t - o];
            __syncthreads();
            if (t >= o) part[t] += xv;
            __syncthreads();
        }
        {
            int run = part[t] - lsum;
            if (base4 + 0 < nbuck) { lexcl[base4 + 0] = run; run += c0; }
            if (base4 + 1 < nbuck) { lexcl[base4 + 1] = run; run += c1; }
            if (base4 + 2 < nbuck) { lexcl[base4 + 2] = run; run += c2; }
            if (base4 + 3 < nbuck) { lexcl[base4 + 3] = run; run += c3; }
        }
        // global reservations (independent of scan results)
        for (int i = t; i < nbuck; i += 256) {
            int c = lhist[i];
            gbase[i] = c ? atomicAdd(&bucket_pos[i], c) : 0;
        }
        __syncthreads();
        // stage edges into LDS, bucket-sorted
#pragma unroll 4
        for (int i = 0; i < ept; ++i) {
            if (slot[i] >= 0) {
                int pos = lexcl[bidx[i]] + slot[i];
                estage[pos] = ed[i];
                bstage[pos] = (unsigned short)bidx[i];
            }
        }
        __syncthreads();
        // emit: consecutive lanes -> same-bucket runs (coalesced-ish writes)
        int m_blk = E - base_e;
        if (m_blk < 0) m_blk = 0;
        if (m_blk > ept * 256) m_blk = ept * 256;
        for (int s = t; s < m_blk; s += 256) {
            int bb = bstage[s];
            int pos = gbase[bb] + (s - lexcl[bb]);
            if (pos < CAP) ebuf[(size_t)bb * CAP + pos] = estage[s];
        }
        return;
    }
    int cb = b - P2B;
    if (cb < ncvt) {
        // ---- cvt role: x (f32) -> xb (bf16), 16B out per thread ----
        long long i = (long long)cb * 256 + t;
        if (i >= n8) return;
        const float4* p = (const float4*)(x + i * 8);
        float4 a = p[0], c = p[1];
        uint4 o;
        o.x = (unsigned)f2bf(a.x) | ((unsigned)f2bf(a.y) << 16);
        o.y = (unsigned)f2bf(a.z) | ((unsigned)f2bf(a.w) << 16);
        o.z = (unsigned)f2bf(c.x) | ((unsigned)f2bf(c.y) << 16);
        o.w = (unsigned)f2bf(c.z) | ((unsigned)f2bf(c.w) << 16);
        ((uint4*)(xb))[i] = o;
        return;
    }
    if (cb < ncvt + 16) {   // W1 frags: Wcat[256][128] = [W1_l; W1_r], 64 frags
        int tid = (cb - ncvt) * 256 + t;   // 4096
        int fi = tid >> 6, lane = tid & 63;
        int ct = fi >> 3, ks = fi & 7;
        int k0 = ks * 32 + (lane >> 4) * 8;
        int n = ct * 16 + (lane & 15);
        unsigned short e[8];
#pragma unroll
        for (int j = 0; j < 8; ++j) {
            int k = k0 + j;
            float v = (k < 128) ? W1l[k * 128 + n] : W1r[(k - 128) * 128 + n];
            e[j] = f2bf(v);
        }
        uint4 o;
        o.x = (unsigned)e[0] | ((unsigned)e[1] << 16);
        o.y = (unsigned)e[2] | ((unsigned)e[3] << 16);
        o.z = (unsigned)e[4] | ((unsigned)e[5] << 16);
        o.w = (unsigned)e[6] | ((unsigned)e[7] << 16);
        w1frag[tid] = o;
        return;
    }
    // W2 frags: Wcat2[128][128] = [W2_l | W2_r], 32 frags
    int tid = (cb - ncvt - 16) * 256 + t;   // 2048
    if (tid >= 2048) return;
    int fi = tid >> 6, lane = tid & 63;
    int ct = fi >> 2, ks = fi & 3;
    int k0 = ks * 32 + (lane >> 4) * 8;
    int n = ct * 16 + (lane & 15);
    unsigned short e[8];
#pragma unroll
    for (int j = 0; j < 8; ++j) {
        int k = k0 + j;
        float v = (n < 64) ? W2l[k * 64 + n] : W2r[k * 64 + (n - 64)];
        e[j] = f2bf(v);
    }
    uint4 o;
    o.x = (unsigned)e[0] | ((unsigned)e[1] << 16);
    o.y = (unsigned)e[2] | ((unsigned)e[3] << 16);
    o.z = (unsigned)e[4] | ((unsigned)e[5] << 16);
    o.w = (unsigned)e[6] | ((unsigned)e[7] << 16);
    w2frag[tid] = o;
}

// pass3: one block per bucket (128 nodes); counts, scan, startcnt + csr
__global__ __launch_bounds__(256) void pass3_finalize(const unsigned* __restrict__ ebuf,
                                                      const int* __restrict__ bucket_pos,
                                                      int nbuck, int N,
                                                      int2* __restrict__ startcnt,
                                                      int* __restrict__ csr) {
    __shared__ int lcnt[128];
    __shared__ int lexcl[128];
    __shared__ int sc[128];
    int b = blockIdx.x;
    int t = threadIdx.x;
    int d0 = b << 7;
    int nb = N - d0; if (nb > 128) nb = 128;
    int m = bucket_pos[b]; if (m > CAP) m = CAP;
    const unsigned* eb = ebuf + (size_t)b * CAP;

    if (t < 128) lcnt[t] = 0;
    __syncthreads();
    for (int j = t; j < m; j += 256) {
        atomicAdd(&lcnt[eb[j] & 127u], 1);
    }
    __syncthreads();
    int v = 0;
    if (t < 128) { v = lcnt[t]; sc[t] = v; }
    __syncthreads();
    for (int o = 1; o < 128; o <<= 1) {
        int x = 0;
        if (t < 128 && t >= o) x = sc[t - o];
        __syncthreads();
        if (t < 128 && t >= o) sc[t] += x;
        __syncthreads();
    }
    if (t < 128) {
        int excl = sc[t] - v;
        lexcl[t] = excl;
        if (t < nb) startcnt[d0 + t] = make_int2(b * CAP + excl, v);
        lcnt[t] = 0;   // reuse as running pos
    }
    __syncthreads();
    for (int j = t; j < m; j += 256) {
        unsigned ed = eb[j];
        int li = (int)(ed & 127u);
        int slot = atomicAdd(&lcnt[li], 1);
        csr[b * CAP + lexcl[li] + slot] = (int)(ed >> 7);
    }
}

// ------- MERGED: mean agg (D=128) + last-finisher fused gemm1+gemm2 -------
// Agg structure identical to the proven 59us agg_mean128_bf. Handoff: unit =
// 64 rows = 16 agg blocks; last finisher runs the unit's gemm (16 rows/wave).
__global__ __launch_bounds__(256, 5) void agg128_gemm(const unsigned short* __restrict__ Xb,
                                                      const int2* __restrict__ startcnt,
                                                      const int* __restrict__ csr,
                                                      unsigned short* __restrict__ meanb,
                                                      const uint4* __restrict__ w1frag,
                                                      const uint4* __restrict__ w2frag,
                                                      const float* __restrict__ b1,
                                                      const float* __restrict__ b2,
                                                      unsigned short* __restrict__ z2,
                                                      float* __restrict__ outw2,
                                                      int* __restrict__ ucnt,
                                                      int n_nodes) {
    __shared__ unsigned short hs[4][16 * HSTRIDE];  // 17408 B (gemm phase)
    __shared__ int lastflag;
    const int lane = threadIdx.x & 63;
    const int quad = lane >> 4, l16 = lane & 15;
    const int wid = threadIdx.x >> 6;

    // ---- agg phase: one node per wave ----
    {
        int node = blockIdx.x * 4 + wid;
        if (node >= n_nodes) node = n_nodes - 1;   // keep thread alive for handoff
        int2 sc2 = startcnt[node];
        int s0 = sc2.x, deg = sc2.y, s1 = s0 + deg;
        f32x2 A0[4], A1[4];
#pragma unroll
        for (int k = 0; k < 4; ++k) { A0[k] = (f32x2){0.f, 0.f}; A1[k] = (f32x2){0.f, 0.f}; }
        int j = s0;
        for (; j + 8 <= s1; j += 8) {
            int p0 = csr[j + quad];
            int p1 = csr[j + 4 + quad];
            uint4 v0 = ((const uint4*)(Xb + (size_t)p0 * 128))[l16];
            uint4 v1 = ((const uint4*)(Xb + (size_t)p1 * 128))[l16];
            accp(v0, A0);
            accp(v1, A1);
        }
        if (j + 4 <= s1) {
            int p = csr[j + quad];
            uint4 v = ((const uint4*)(Xb + (size_t)p * 128))[l16];
            accp(v, A0);
            j += 4;
        }
        if (j < s1) {  // masked tail, 1..3 edges
            int jj = j + quad;
            int p = csr[(jj < s1) ? jj : (s1 - 1)];
            float w = (jj < s1) ? 1.0f : 0.0f;
            uint4 v = ((const uint4*)(Xb + (size_t)p * 128))[l16];
            accpw(v, w, A1);
        }
        float r[8];
#pragma unroll
        for (int k = 0; k < 4; ++k) {
            f32x2 s = A0[k] + A1[k];
            r[2 * k] = s.x;
            r[2 * k + 1] = s.y;
        }
#pragma unroll
        for (int k = 0; k < 8; ++k) r[k] += __shfl(r[k], lane ^ 16);
#pragma unroll
        for (int k = 0; k < 8; ++k) r[k] += __shfl(r[k], lane ^ 32);
        float inv = (deg > 0) ? 1.0f / (float)deg : 0.0f;
        if (quad == 0) {
            uint4 o;
            o.x = (unsigned)f2bf(r[0] * inv) | ((unsigned)f2bf(r[1] * inv) << 16);
            o.y = (unsigned)f2bf(r[2] * inv) | ((unsigned)f2bf(r[3] * inv) << 16);
            o.z = (unsigned)f2bf(r[4] * inv) | ((unsigned)f2bf(r[5] * inv) << 16);
            o.w = (unsigned)f2bf(r[6] * inv) | ((unsigned)f2bf(r[7] * inv) << 16);
            ((uint4*)(meanb + (size_t)node * 128))[l16] = o;
        }
    }

    // ---- handoff: last finisher of each 64-row unit runs its gemm ----
    const int u = blockIdx.x >> 4;          // 16 blocks (64 nodes) per unit
    __syncthreads();                        // drains all waves' meanb stores
    if (threadIdx.x == 0) {
        __threadfence();                    // agent release: wb L2 before signal
        int rows = n_nodes - (u << 6);
        int expect = (rows >= 64) ? 16 : ((rows + 3) >> 2);
        int old = atomicAdd(&ucnt[u], 1);
        lastflag = (old == expect - 1) ? 1 : 0;
    }
    __syncthreads();
    if (!lastflag) return;
    __threadfence();                        // acquire: inv stale lines

    // ---- gemm phase: rows [64u, 64u+64), 16 rows per wave ----
    const int m0 = (u << 6) + wid * 16;
    unsigned short* hsw = &hs[wid][0];
    const uint4* w1p = w1frag + lane;
    const uint4* w2p = w2frag + lane;

    bf16x8 af[8];
    {
        int row = m0 + l16;
        int rowc = (row < n_nodes) ? row : (n_nodes - 1);
        const uint4* mrow = (const uint4*)(meanb + (size_t)rowc * 128);
        const uint4* xrow = (const uint4*)(Xb + (size_t)rowc * 128);
#pragma unroll
        for (int ks = 0; ks < 4; ++ks) {
            af[ks]     = __builtin_bit_cast(bf16x8, mrow[ks * 4 + quad]);
            af[ks + 4] = __builtin_bit_cast(bf16x8, xrow[ks * 4 + quad]);
        }
    }

    // gemm1: stream W1, one load -> one MFMA; h -> LDS scratch
    for (int ct = 0; ct < 8; ++ct) {
        uint4 wc[8];
#pragma unroll
        for (int ks = 0; ks < 8; ++ks) wc[ks] = w1p[(ct * 8 + ks) * 64];
        f32x4 a0 = (f32x4){0.f, 0.f, 0.f, 0.f};
#pragma unroll
        for (int ks = 0; ks < 8; ++ks) {
            bf16x8 bf = __builtin_bit_cast(bf16x8, wc[ks]);
            a0 = __builtin_amdgcn_mfma_f32_16x16x32_bf16(af[ks], bf, a0, 0, 0, 0);
        }
        int col = ct * 16 + l16;
        float bb = b1[col];
#pragma unroll
        for (int r = 0; r < 4; ++r) {
            hsw[(quad * 4 + r) * HSTRIDE + col] = f2bf(fmaxf(a0[r] + bb, 0.f));
        }
    }

    // transpose read: A-frags of h (row = l16, k = ks*32+quad*8+j)
    bf16x8 af2[4];
#pragma unroll
    for (int ks = 0; ks < 4; ++ks) {
        uint4 tt = *(const uint4*)(hsw + l16 * HSTRIDE + ks * 32 + quad * 8);
        af2[ks] = __builtin_bit_cast(bf16x8, tt);
    }

    // gemm2: stream W2, one load -> one MFMA; z2 (bf16) + x-side -> out (f32)
    for (int ct = 0; ct < 8; ++ct) {
        uint4 wc2[4];
#pragma unroll
        for (int ks = 0; ks < 4; ++ks) wc2[ks] = w2p[(ct * 4 + ks) * 64];
        f32x4 a0 = (f32x4){0.f, 0.f, 0.f, 0.f};
#pragma unroll
        for (int ks = 0; ks < 4; ++ks) {
            bf16x8 bf = __builtin_bit_cast(bf16x8, wc2[ks]);
            a0 = __builtin_amdgcn_mfma_f32_16x16x32_bf16(af2[ks], bf, a0, 0, 0, 0);
        }
        int col = ct * 16 + l16;
#pragma unroll
        for (int r = 0; r < 4; ++r) {
            int orow = m0 + quad * 4 + r;
            if (orow < n_nodes) {
                if (col < 64) {
                    z2[(size_t)orow * 64 + col] = f2bf(a0[r]);
                } else {
                    outw2[(size_t)orow * 64 + (col - 64)] = a0[r] + b2[col - 64];
                }
            }
        }
    }
}

// ---------------- mean aggregation, D=64 bf16, DUAL-NODE waves, +out -------
// R17: 2 nodes/wave. Epilogue: out already holds the x-side (gemm wrote it);
// read-modify-write out += mean/deg.
__global__ __launch_bounds__(256) void agg_mean64_bf_ep(const unsigned short* __restrict__ Zb,
                                                        const int2* __restrict__ startcnt,
                                                        const int* __restrict__ csr,
                                                        float* __restrict__ out,
                                                        int n_nodes) {
    int node = blockIdx.x * 8 + (threadIdx.x >> 5);   // 8 nodes per block
    if (node >= n_nodes) return;
    int lane = threadIdx.x & 63;
    int hl = lane & 31;          // lane within half
    int oct4 = hl >> 3;          // 0..3
    int l8 = hl & 7;
    int2 sc2 = startcnt[node];
    int s0 = sc2.x, deg = sc2.y, s1 = s0 + deg;
    f32x2 A0[4], A1[4];
#pragma unroll
    for (int k = 0; k < 4; ++k) { A0[k] = (f32x2){0.f, 0.f}; A1[k] = (f32x2){0.f, 0.f}; }
    int j = s0;
    for (; j + 8 <= s1; j += 8) {
        int p0 = csr[j + oct4];
        int p1 = csr[j + 4 + oct4];
        uint4 v0 = ((const uint4*)(Zb + (size_t)p0 * 64))[l8];
        uint4 v1 = ((const uint4*)(Zb + (size_t)p1 * 64))[l8];
        accp(v0, A0);
        accp(v1, A1);
    }
    if (j + 4 <= s1) {
        int p = csr[j + oct4];
        uint4 v = ((const uint4*)(Zb + (size_t)p * 64))[l8];
        accp(v, A0);
        j += 4;
    }
    if (j < s1) {  // masked tail, 1..3 edges
        int jj = j + oct4;
        int p = csr[(jj < s1) ? jj : (s1 - 1)];
        float w = (jj < s1) ? 1.0f : 0.0f;
        uint4 v = ((const uint4*)(Zb + (size_t)p * 64))[l8];
        accpw(v, w, A1);
    }
    float r[8];
#pragma unroll
    for (int k = 0; k < 4; ++k) {
        f32x2 s = A0[k] + A1[k];
        r[2 * k] = s.x;
        r[2 * k + 1] = s.y;
    }
    // reduce across 4 octs within each 32-lane half (xor 8, 16 stay in-half)
#pragma unroll
    for (int k = 0; k < 8; ++k) r[k] += __shfl(r[k], lane ^ 8);
#pragma unroll
    for (int k = 0; k < 8; ++k) r[k] += __shfl(r[k], lane ^ 16);
    float inv = (deg > 0) ? 1.0f / (float)deg : 0.0f;
    if (oct4 == 0) {
        float4* op = (float4*)(out + (size_t)node * 64 + l8 * 8);
        float4 w0 = op[0], w1 = op[1];
        float4 o0, o1;
        o0.x = r[0] * inv + w0.x; o0.y = r[1] * inv + w0.y;
        o0.z = r[2] * inv + w0.z; o0.w = r[3] * inv + w0.w;
        o1.x = r[4] * inv + w1.x; o1.y = r[5] * inv + w1.y;
        o1.z = r[6] * inv + w1.z; o1.w = r[7] * inv + w1.w;
        op[0] = o0; op[1] = o1;
    }
}

extern "C" void kernel_launch(void* const* d_in, const int* in_sizes, int n_in,
                              void* d_out, int out_size, void* d_ws, size_t ws_size,
                              hipStream_t stream) {
    const float* x    = (const float*)d_in[0];
    const float* W1_l = (const float*)d_in[1];
    const float* b1   = (const float*)d_in[2];
    const float* W1_r = (const float*)d_in[3];
    const float* W2_l = (const float*)d_in[4];
    const float* b2   = (const float*)d_in[5];
    const float* W2_r = (const float*)d_in[6];
    const void*  ei   = d_in[7];
    float* out = (float*)d_out;

    const int N = in_sizes[0] / 128;      // 100000
    const int E = in_sizes[7] / 2;        // 1600000
    const int nbuck = (N + 127) >> 7;     // 782

    // workspace layout (~86 MB)
    uintptr_t base = (uintptr_t)d_ws;
    int* bucket_pos = (int*)(base + 64);                      // nbuck ints
    int* ucnt = (int*)(base + 4096);                          // 1563 ints
    int2* startcnt = (int2*)(base + 16384);                   // N int2
    int* csr = (int*)(((uintptr_t)(startcnt + N) + 255) & ~(uintptr_t)255); // nbuck*CAP
    uintptr_t p = ((uintptr_t)(csr + (size_t)nbuck * CAP) + 255) & ~(uintptr_t)255;
    unsigned short* xb    = (unsigned short*)p; p += (size_t)N * 128 * 2;   // bf16 x
    unsigned short* meanb = (unsigned short*)p; p += (size_t)N * 128 * 2;   // ebuf / bf16 mean
    unsigned short* hbr   = (unsigned short*)p; p += (size_t)N * 128 * 2;   // z2 region
    uint4* w1frag = (uint4*)p; p += 4096 * 16;
    uint4* w2frag = (uint4*)p; p += 2048 * 16;
    unsigned* ebuf = (unsigned*)meanb;     // nbuck*CAP uints; dead before merged writes meanb
    unsigned short* z2 = hbr;              // bf16 N*64; x-side gemm output -> out directly

    const int* ei32 = (const int*)ei;
    const long long* ei64 = (const long long*)ei;

    // zero bucket counters + unit counters (one memset)
    hipMemsetAsync((void*)base, 0, 16384, stream);

    long long n8 = (long long)N * 128 / 8;
    int ncvt = (int)((n8 + 255) / 256);
    int ept = (E + P2B * 256 - 1) / (P2B * 256);   // 13 for E=1.6M (<= MAXEPT)

    // fused front: pass2 sorted-partition | cvt | w frags
    fused_front<<<P2B + ncvt + 24, 256, 0, stream>>>(
        x, xb, n8, ncvt, W1_l, W1_r, w1frag, W2_l, W2_r, w2frag,
        ei32, ei64, E, ept, nbuck, N, bucket_pos, ebuf);

    pass3_finalize<<<nbuck, 256, 0, stream>>>(ebuf, bucket_pos, nbuck, N,
                                              startcnt, csr);

    int ablocks = (N + 3) / 4;

    // merged: layer-1 agg + overlapped last-finisher gemm1+gemm2
    agg128_gemm<<<ablocks, 256, 0, stream>>>(xb, startcnt, csr, meanb,
                                             w1frag, w2frag, b1, b2,
                                             z2, out, ucnt, N);

    // layer 2 agg (commuted, dual-node waves) + in-place epilogue on out
    int a64blocks = (N + 7) / 8;
    agg_mean64_bf_ep<<<a64blocks, 256, 0, stream>>>(z2, startcnt, csr, out, N);
}

// Round 9
// 272.553 us; speedup vs baseline: 11.0506x; 11.0506x over previous
//
#include <hip/hip_runtime.h>
#include <hip/hip_bf16.h>
#include <cstdint>

// GraphSAGE 2-layer, bf16 features + fp32 accumulate, MFMA GEMMs.
// Layer1: h   = relu([mean_agg(x) | x] @ [W1_l; W1_r] + b1)   (K=256 MFMA GEMM)
// Layer2: out = mean_agg(h @ W2_l) + h @ W2_r + b2            (agg commutes w/ linear)
// R19 pipeline (5 dispatches):
//   memset(bucket_pos) -> fused_front (pass2 sorted-partition|cvt|wfrags)
//   -> pass3 -> agg16_gemm (1024-thr block: 16 waves agg 16 nodes -> barrier
//   -> waves 0-7 gemm1, waves 8-15 gemm2; mean lives in LDS only)
//   -> agg64 (dual-node, in-place epilogue on out)
// R18 FALSIFIED (2880us, VALUBusy 1.4%): per-block __threadfence (device
// release) = buffer_wbl2/inv L2 FLUSH on gfx950; 25000 flushes serialized the
// machine + destroyed gather L2/L3 residency. NEVER use per-block device-scope
// fence handoffs. R19 gets the same overlap with __syncthreads only: block
// owns its full 16-row gemm tile (N=100000=6250x16 exactly, no tail).
// Per-wave agg structure BYTE-IDENTICAL to proven 59us kernel; 32 gather
// chains/CU if 2 blocks/CU (needs VGPR<=64 -> launch_bounds(1024,8)).
// Bonus: meanb global round-trip eliminated (mean -> LDS -> A-frags).
// LEDGER: agg128 59=floor(177.8MB@3.5TB/s fabric); agg64 ~41 (R17 WIN);
// front+pass3+gemm ~60-75; ~30 harness dispatches/iter fixed. R16 sorted
// scatter kept (~1us). FALSIFIED: R10 dim-slab, R11 shfl-bcast, R13 per-
// bucket serial fusion (kills TLP), R14 16row gemm standalone, R15 range
// split (+5.6), R18 fence handoff. fdot2_f32_bf16 WRONG on gfx950 (R6).

typedef __bf16 bf16x8 __attribute__((ext_vector_type(8)));
typedef float f32x4 __attribute__((ext_vector_type(4)));
typedef float f32x2 __attribute__((ext_vector_type(2)));

#define MAXBUCK 800   // >= ceil(102400/128)
#define CAP 2560      // per-bucket edge capacity; mean 2046, sigma ~45
#define MAXEPT 16
#define P2B 512       // pass2 blocks
#define P2E (MAXEPT * 256)   // staging capacity (4096; ept=13 uses 3328)
#define HSTRIDE 136   // bf16 elems per scratch row (272B, 16B-aligned)

__device__ __forceinline__ unsigned short f2bf(float f) {
    union { float f; unsigned int u; } v; v.f = f;
    unsigned int u = v.u;
    unsigned int r = ((u >> 16) & 1u) + 0x7fffu;
    return (unsigned short)((u + r) >> 16);
}

// unpack uint (2 bf16) -> f32x2 {lo, hi}
__device__ __forceinline__ f32x2 up2(unsigned int u) {
    uint2 t; t.x = u << 16; t.y = u & 0xffff0000u;
    return __builtin_bit_cast(f32x2, t);
}
__device__ __forceinline__ void accp(const uint4& v, f32x2* a) {
    a[0] += up2(v.x);
    a[1] += up2(v.y);
    a[2] += up2(v.z);
    a[3] += up2(v.w);
}
__device__ __forceinline__ void accpw(const uint4& v, float w, f32x2* a) {
    a[0] += up2(v.x) * w;
    a[1] += up2(v.y) * w;
    a[2] += up2(v.z) * w;
    a[3] += up2(v.w) * w;
}

__device__ __forceinline__ int edge_val(const int* ei32, const long long* ei64,
                                        int is64, size_t idx) {
    return is64 ? (int)ei64[idx] : ei32[idx];
}

// ---------------- FUSED FRONT: pass2 sorted-partition | cvt | w frags ------
__global__ __launch_bounds__(256) void fused_front(const float* __restrict__ x,
                                                   unsigned short* __restrict__ xb,
                                                   long long n8, int ncvt,
                                                   const float* __restrict__ W1l,
                                                   const float* __restrict__ W1r,
                                                   uint4* __restrict__ w1frag,
                                                   const float* __restrict__ W2l,
                                                   const float* __restrict__ W2r,
                                                   uint4* __restrict__ w2frag,
                                                   const int* __restrict__ ei32,
                                                   const long long* __restrict__ ei64,
                                                   int E, int ept, int nbuck,
                                                   int n_nodes,
                                                   int* __restrict__ bucket_pos,
                                                   unsigned* __restrict__ ebuf) {
    __shared__ int lhist[MAXBUCK];
    __shared__ int lexcl[MAXBUCK];
    __shared__ int gbase[MAXBUCK];
    __shared__ int part[256];
    __shared__ unsigned estage[P2E];
    __shared__ unsigned short bstage[P2E];
    int b = blockIdx.x;
    int t = threadIdx.x;
    if (b < P2B) {
        // ---- pass2 role: partition edges into padded buckets, sorted ----
        for (int i = t; i < nbuck; i += 256) lhist[i] = 0;
        __syncthreads();
        int is64;
        {   // self-detect: 8 uniform loads; garbage-as-int64 fails bounds
            int ok = 1;
            for (int i = 0; i < 8; ++i) {
                long long v = ei64[i];
                if (v < 0 || v >= n_nodes) ok = 0;
            }
            is64 = ok;
        }
        int base_e = b * (ept * 256);
        unsigned ed[MAXEPT];
        int bidx[MAXEPT];
        int slot[MAXEPT];
#pragma unroll 4
        for (int i = 0; i < ept; ++i) {
            int e = base_e + i * 256 + t;
            if (e < E) {
                int s = edge_val(ei32, ei64, is64, (size_t)e);
                int d = edge_val(ei32, ei64, is64, (size_t)E + e);
                ed[i] = ((unsigned)s << 7) | (unsigned)(d & 127);
                bidx[i] = d >> 7;
                slot[i] = atomicAdd(&lhist[d >> 7], 1);
            } else {
                slot[i] = -1;
            }
        }
        __syncthreads();
        // block-local exclusive scan of lhist[0..nbuck) (4 buckets/thread)
        int base4 = t * 4;
        int c0 = (base4 + 0 < nbuck) ? lhist[base4 + 0] : 0;
        int c1 = (base4 + 1 < nbuck) ? lhist[base4 + 1] : 0;
        int c2 = (base4 + 2 < nbuck) ? lhist[base4 + 2] : 0;
        int c3 = (base4 + 3 < nbuck) ? lhist[base4 + 3] : 0;
        int lsum = c0 + c1 + c2 + c3;
        part[t] = lsum;
        __syncthreads();
        for (int o = 1; o < 256; o <<= 1) {
            int xv = 0;
            if (t >= o) xv = part[t - o];
            __syncthreads();
            if (t >= o) part[t] += xv;
            __syncthreads();
        }
        {
            int run = part[t] - lsum;
            if (base4 + 0 < nbuck) { lexcl[base4 + 0] = run; run += c0; }
            if (base4 + 1 < nbuck) { lexcl[base4 + 1] = run; run += c1; }
            if (base4 + 2 < nbuck) { lexcl[base4 + 2] = run; run += c2; }
            if (base4 + 3 < nbuck) { lexcl[base4 + 3] = run; run += c3; }
        }
        // global reservations (independent of scan results)
        for (int i = t; i < nbuck; i += 256) {
            int c = lhist[i];
            gbase[i] = c ? atomicAdd(&bucket_pos[i], c) : 0;
        }
        __syncthreads();
        // stage edges into LDS, bucket-sorted
#pragma unroll 4
        for (int i = 0; i < ept; ++i) {
            if (slot[i] >= 0) {
                int pos = lexcl[bidx[i]] + slot[i];
                estage[pos] = ed[i];
                bstage[pos] = (unsigned short)bidx[i];
            }
        }
        __syncthreads();
        // emit: consecutive lanes -> same-bucket runs (coalesced-ish writes)
        int m_blk = E - base_e;
        if (m_blk < 0) m_blk = 0;
        if (m_blk > ept * 256) m_blk = ept * 256;
        for (int s = t; s < m_blk; s += 256) {
            int bb = bstage[s];
            int pos = gbase[bb] + (s - lexcl[bb]);
            if (pos < CAP) ebuf[(size_t)bb * CAP + pos] = estage[s];
        }
        return;
    }
    int cb = b - P2B;
    if (cb < ncvt) {
        // ---- cvt role: x (f32) -> xb (bf16), 16B out per thread ----
        long long i = (long long)cb * 256 + t;
        if (i >= n8) return;
        const float4* p = (const float4*)(x + i * 8);
        float4 a = p[0], c = p[1];
        uint4 o;
        o.x = (unsigned)f2bf(a.x) | ((unsigned)f2bf(a.y) << 16);
        o.y = (unsigned)f2bf(a.z) | ((unsigned)f2bf(a.w) << 16);
        o.z = (unsigned)f2bf(c.x) | ((unsigned)f2bf(c.y) << 16);
        o.w = (unsigned)f2bf(c.z) | ((unsigned)f2bf(c.w) << 16);
        ((uint4*)(xb))[i] = o;
        return;
    }
    if (cb < ncvt + 16) {   // W1 frags: Wcat[256][128] = [W1_l; W1_r], 64 frags
        int tid = (cb - ncvt) * 256 + t;   // 4096
        int fi = tid >> 6, lane = tid & 63;
        int ct = fi >> 3, ks = fi & 7;
        int k0 = ks * 32 + (lane >> 4) * 8;
        int n = ct * 16 + (lane & 15);
        unsigned short e[8];
#pragma unroll
        for (int j = 0; j < 8; ++j) {
            int k = k0 + j;
            float v = (k < 128) ? W1l[k * 128 + n] : W1r[(k - 128) * 128 + n];
            e[j] = f2bf(v);
        }
        uint4 o;
        o.x = (unsigned)e[0] | ((unsigned)e[1] << 16);
        o.y = (unsigned)e[2] | ((unsigned)e[3] << 16);
        o.z = (unsigned)e[4] | ((unsigned)e[5] << 16);
        o.w = (unsigned)e[6] | ((unsigned)e[7] << 16);
        w1frag[tid] = o;
        return;
    }
    // W2 frags: Wcat2[128][128] = [W2_l | W2_r], 32 frags
    int tid = (cb - ncvt - 16) * 256 + t;   // 2048
    if (tid >= 2048) return;
    int fi = tid >> 6, lane = tid & 63;
    int ct = fi >> 2, ks = fi & 3;
    int k0 = ks * 32 + (lane >> 4) * 8;
    int n = ct * 16 + (lane & 15);
    unsigned short e[8];
#pragma unroll
    for (int j = 0; j < 8; ++j) {
        int k = k0 + j;
        float v = (n < 64) ? W2l[k * 64 + n] : W2r[k * 64 + (n - 64)];
        e[j] = f2bf(v);
    }
    uint4 o;
    o.x = (unsigned)e[0] | ((unsigned)e[1] << 16);
    o.y = (unsigned)e[2] | ((unsigned)e[3] << 16);
    o.z = (unsigned)e[4] | ((unsigned)e[5] << 16);
    o.w = (unsigned)e[6] | ((unsigned)e[7] << 16);
    w2frag[tid] = o;
}

// pass3: one block per bucket (128 nodes); counts, scan, startcnt + csr
__global__ __launch_bounds__(256) void pass3_finalize(const unsigned* __restrict__ ebuf,
                                                      const int* __restrict__ bucket_pos,
                                                      int nbuck, int N,
                                                      int2* __restrict__ startcnt,
                                                      int* __restrict__ csr) {
    __shared__ int lcnt[128];
    __shared__ int lexcl[128];
    __shared__ int sc[128];
    int b = blockIdx.x;
    int t = threadIdx.x;
    int d0 = b << 7;
    int nb = N - d0; if (nb > 128) nb = 128;
    int m = bucket_pos[b]; if (m > CAP) m = CAP;
    const unsigned* eb = ebuf + (size_t)b * CAP;

    if (t < 128) lcnt[t] = 0;
    __syncthreads();
    for (int j = t; j < m; j += 256) {
        atomicAdd(&lcnt[eb[j] & 127u], 1);
    }
    __syncthreads();
    int v = 0;
    if (t < 128) { v = lcnt[t]; sc[t] = v; }
    __syncthreads();
    for (int o = 1; o < 128; o <<= 1) {
        int x = 0;
        if (t < 128 && t >= o) x = sc[t - o];
        __syncthreads();
        if (t < 128 && t >= o) sc[t] += x;
        __syncthreads();
    }
    if (t < 128) {
        int excl = sc[t] - v;
        lexcl[t] = excl;
        if (t < nb) startcnt[d0 + t] = make_int2(b * CAP + excl, v);
        lcnt[t] = 0;   // reuse as running pos
    }
    __syncthreads();
    for (int j = t; j < m; j += 256) {
        unsigned ed = eb[j];
        int li = (int)(ed & 127u);
        int slot = atomicAdd(&lcnt[li], 1);
        csr[b * CAP + lexcl[li] + slot] = (int)(ed >> 7);
    }
}

// ------- MERGED: 16-wave block = 16-node agg + in-block gemm1+gemm2 -------
// Per-wave agg identical to the proven 59us kernel (1 node/wave, direct csr
// loads). Mean rows -> LDS (no global meanb). After ONE __syncthreads:
// waves 0-7 each compute one ct of gemm1 (h -> LDS), barrier, waves 8-15
// each compute one ct of gemm2 -> z2 (bf16) + x-side directly into out (f32).
// No fences, no atomics, no cross-block communication.
__global__ __launch_bounds__(1024, 8) void agg16_gemm(const unsigned short* __restrict__ Xb,
                                                      const int2* __restrict__ startcnt,
                                                      const int* __restrict__ csr,
                                                      const uint4* __restrict__ w1frag,
                                                      const uint4* __restrict__ w2frag,
                                                      const float* __restrict__ b1,
                                                      const float* __restrict__ b2,
                                                      unsigned short* __restrict__ z2,
                                                      float* __restrict__ outw2,
                                                      int n_nodes) {
    __shared__ unsigned short ms[16 * HSTRIDE];   // mean rows (bf16)
    __shared__ unsigned short xs[16 * HSTRIDE];   // x rows (bf16)
    __shared__ unsigned short hsb[16 * HSTRIDE];  // h rows (bf16)
    const int t = threadIdx.x;
    const int wid = t >> 6;            // 0..15
    const int lane = t & 63;
    const int quad = lane >> 4, l16 = lane & 15;

    // ---- agg phase: one node per wave (proven structure) ----
    {
        int node = blockIdx.x * 16 + wid;
        if (node >= n_nodes) node = n_nodes - 1;   // safety (N%16==0 in practice)
        // stage this node's x row into LDS (L2-hot stream)
        if (quad == 0) {
            *(uint4*)(xs + wid * HSTRIDE + l16 * 8) =
                ((const uint4*)(Xb + (size_t)node * 128))[l16];
        }
        int2 sc2 = startcnt[node];
        int s0 = sc2.x, deg = sc2.y, s1 = s0 + deg;
        f32x2 A0[4], A1[4];
#pragma unroll
        for (int k = 0; k < 4; ++k) { A0[k] = (f32x2){0.f, 0.f}; A1[k] = (f32x2){0.f, 0.f}; }
        int j = s0;
        for (; j + 8 <= s1; j += 8) {
            int p0 = csr[j + quad];
            int p1 = csr[j + 4 + quad];
            uint4 v0 = ((const uint4*)(Xb + (size_t)p0 * 128))[l16];
            uint4 v1 = ((const uint4*)(Xb + (size_t)p1 * 128))[l16];
            accp(v0, A0);
            accp(v1, A1);
        }
        if (j + 4 <= s1) {
            int p = csr[j + quad];
            uint4 v = ((const uint4*)(Xb + (size_t)p * 128))[l16];
            accp(v, A0);
            j += 4;
        }
        if (j < s1) {  // masked tail, 1..3 edges
            int jj = j + quad;
            int p = csr[(jj < s1) ? jj : (s1 - 1)];
            float w = (jj < s1) ? 1.0f : 0.0f;
            uint4 v = ((const uint4*)(Xb + (size_t)p * 128))[l16];
            accpw(v, w, A1);
        }
        float r[8];
#pragma unroll
        for (int k = 0; k < 4; ++k) {
            f32x2 s = A0[k] + A1[k];
            r[2 * k] = s.x;
            r[2 * k + 1] = s.y;
        }
#pragma unroll
        for (int k = 0; k < 8; ++k) r[k] += __shfl(r[k], lane ^ 16);
#pragma unroll
        for (int k = 0; k < 8; ++k) r[k] += __shfl(r[k], lane ^ 32);
        float inv = (deg > 0) ? 1.0f / (float)deg : 0.0f;
        if (quad == 0) {
            uint4 o;
            o.x = (unsigned)f2bf(r[0] * inv) | ((unsigned)f2bf(r[1] * inv) << 16);
            o.y = (unsigned)f2bf(r[2] * inv) | ((unsigned)f2bf(r[3] * inv) << 16);
            o.z = (unsigned)f2bf(r[4] * inv) | ((unsigned)f2bf(r[5] * inv) << 16);
            o.w = (unsigned)f2bf(r[6] * inv) | ((unsigned)f2bf(r[7] * inv) << 16);
            *(uint4*)(ms + wid * HSTRIDE + l16 * 8) = o;
        }
    }
    __syncthreads();   // means + x rows visible block-wide

    // ---- gemm1: waves 0-7, one ct each; A = [mean | x] from LDS ----
    if (wid < 8) {
        bf16x8 af[8];
#pragma unroll
        for (int ks = 0; ks < 4; ++ks) {
            af[ks] = __builtin_bit_cast(bf16x8,
                *(const uint4*)(ms + l16 * HSTRIDE + ks * 32 + quad * 8));
            af[ks + 4] = __builtin_bit_cast(bf16x8,
                *(const uint4*)(xs + l16 * HSTRIDE + ks * 32 + quad * 8));
        }
        const uint4* w1p = w1frag + lane;
        f32x4 a0 = (f32x4){0.f, 0.f, 0.f, 0.f};
#pragma unroll
        for (int ks = 0; ks < 8; ++ks) {
            uint4 wc = w1p[(wid * 8 + ks) * 64];
            a0 = __builtin_amdgcn_mfma_f32_16x16x32_bf16(
                af[ks], __builtin_bit_cast(bf16x8, wc), a0, 0, 0, 0);
        }
        int col = wid * 16 + l16;
        float bb = b1[col];
#pragma unroll
        for (int r = 0; r < 4; ++r) {
            hsb[(quad * 4 + r) * HSTRIDE + col] = f2bf(fmaxf(a0[r] + bb, 0.f));
        }
    }
    __syncthreads();   // h complete

    // ---- gemm2: waves 8-15, one ct each; A = h (transpose-read LDS) ----
    if (wid >= 8) {
        int ct = wid - 8;
        bf16x8 af2[4];
#pragma unroll
        for (int ks = 0; ks < 4; ++ks) {
            af2[ks] = __builtin_bit_cast(bf16x8,
                *(const uint4*)(hsb + l16 * HSTRIDE + ks * 32 + quad * 8));
        }
        const uint4* w2p = w2frag + lane;
        f32x4 a0 = (f32x4){0.f, 0.f, 0.f, 0.f};
#pragma unroll
        for (int ks = 0; ks < 4; ++ks) {
            uint4 wc2 = w2p[(ct * 4 + ks) * 64];
            a0 = __builtin_amdgcn_mfma_f32_16x16x32_bf16(
                af2[ks], __builtin_bit_cast(bf16x8, wc2), a0, 0, 0, 0);
        }
        int col = ct * 16 + l16;
#pragma unroll
        for (int r = 0; r < 4; ++r) {
            int orow = blockIdx.x * 16 + quad * 4 + r;
            if (orow < n_nodes) {
                if (col < 64) {
                    z2[(size_t)orow * 64 + col] = f2bf(a0[r]);
                } else {
                    outw2[(size_t)orow * 64 + (col - 64)] = a0[r] + b2[col - 64];
                }
            }
        }
    }
}

// ---------------- mean aggregation, D=64 bf16, DUAL-NODE waves, +out -------
// R17: 2 nodes/wave. Epilogue: out already holds the x-side (gemm wrote it);
// read-modify-write out += mean/deg.
__global__ __launch_bounds__(256) void agg_mean64_bf_ep(const unsigned short* __restrict__ Zb,
                                                        const int2* __restrict__ startcnt,
                                                        const int* __restrict__ csr,
                                                        float* __restrict__ out,
                                                        int n_nodes) {
    int node = blockIdx.x * 8 + (threadIdx.x >> 5);   // 8 nodes per block
    if (node >= n_nodes) return;
    int lane = threadIdx.x & 63;
    int hl = lane & 31;          // lane within half
    int oct4 = hl >> 3;          // 0..3
    int l8 = hl & 7;
    int2 sc2 = startcnt[node];
    int s0 = sc2.x, deg = sc2.y, s1 = s0 + deg;
    f32x2 A0[4], A1[4];
#pragma unroll
    for (int k = 0; k < 4; ++k) { A0[k] = (f32x2){0.f, 0.f}; A1[k] = (f32x2){0.f, 0.f}; }
    int j = s0;
    for (; j + 8 <= s1; j += 8) {
        int p0 = csr[j + oct4];
        int p1 = csr[j + 4 + oct4];
        uint4 v0 = ((const uint4*)(Zb + (size_t)p0 * 64))[l8];
        uint4 v1 = ((const uint4*)(Zb + (size_t)p1 * 64))[l8];
        accp(v0, A0);
        accp(v1, A1);
    }
    if (j + 4 <= s1) {
        int p = csr[j + oct4];
        uint4 v = ((const uint4*)(Zb + (size_t)p * 64))[l8];
        accp(v, A0);
        j += 4;
    }
    if (j < s1) {  // masked tail, 1..3 edges
        int jj = j + oct4;
        int p = csr[(jj < s1) ? jj : (s1 - 1)];
        float w = (jj < s1) ? 1.0f : 0.0f;
        uint4 v = ((const uint4*)(Zb + (size_t)p * 64))[l8];
        accpw(v, w, A1);
    }
    float r[8];
#pragma unroll
    for (int k = 0; k < 4; ++k) {
        f32x2 s = A0[k] + A1[k];
        r[2 * k] = s.x;
        r[2 * k + 1] = s.y;
    }
    // reduce across 4 octs within each 32-lane half (xor 8, 16 stay in-half)
#pragma unroll
    for (int k = 0; k < 8; ++k) r[k] += __shfl(r[k], lane ^ 8);
#pragma unroll
    for (int k = 0; k < 8; ++k) r[k] += __shfl(r[k], lane ^ 16);
    float inv = (deg > 0) ? 1.0f / (float)deg : 0.0f;
    if (oct4 == 0) {
        float4* op = (float4*)(out + (size_t)node * 64 + l8 * 8);
        float4 w0 = op[0], w1 = op[1];
        float4 o0, o1;
        o0.x = r[0] * inv + w0.x; o0.y = r[1] * inv + w0.y;
        o0.z = r[2] * inv + w0.z; o0.w = r[3] * inv + w0.w;
        o1.x = r[4] * inv + w1.x; o1.y = r[5] * inv + w1.y;
        o1.z = r[6] * inv + w1.z; o1.w = r[7] * inv + w1.w;
        op[0] = o0; op[1] = o1;
    }
}

extern "C" void kernel_launch(void* const* d_in, const int* in_sizes, int n_in,
                              void* d_out, int out_size, void* d_ws, size_t ws_size,
                              hipStream_t stream) {
    const float* x    = (const float*)d_in[0];
    const float* W1_l = (const float*)d_in[1];
    const float* b1   = (const float*)d_in[2];
    const float* W1_r = (const float*)d_in[3];
    const float* W2_l = (const float*)d_in[4];
    const float* b2   = (const float*)d_in[5];
    const float* W2_r = (const float*)d_in[6];
    const void*  ei   = d_in[7];
    float* out = (float*)d_out;

    const int N = in_sizes[0] / 128;      // 100000
    const int E = in_sizes[7] / 2;        // 1600000
    const int nbuck = (N + 127) >> 7;     // 782

    // workspace layout (~86 MB)
    uintptr_t base = (uintptr_t)d_ws;
    int* bucket_pos = (int*)(base + 64);                      // nbuck ints
    int2* startcnt = (int2*)(base + 8192);                    // N int2
    int* csr = (int*)(((uintptr_t)(startcnt + N) + 255) & ~(uintptr_t)255); // nbuck*CAP
    uintptr_t p = ((uintptr_t)(csr + (size_t)nbuck * CAP) + 255) & ~(uintptr_t)255;
    unsigned short* xb    = (unsigned short*)p; p += (size_t)N * 128 * 2;   // bf16 x
    unsigned short* ebr   = (unsigned short*)p; p += (size_t)N * 128 * 2;   // ebuf region
    unsigned short* hbr   = (unsigned short*)p; p += (size_t)N * 128 * 2;   // z2 region
    uint4* w1frag = (uint4*)p; p += 4096 * 16;
    uint4* w2frag = (uint4*)p; p += 2048 * 16;
    unsigned* ebuf = (unsigned*)ebr;       // nbuck*CAP uints
    unsigned short* z2 = hbr;              // bf16 N*64; x-side gemm output -> out directly

    const int* ei32 = (const int*)ei;
    const long long* ei64 = (const long long*)ei;

    // zero bucket counters (pass2 blocks self-detect edge dtype)
    hipMemsetAsync(bucket_pos, 0, (size_t)nbuck * sizeof(int), stream);

    long long n8 = (long long)N * 128 / 8;
    int ncvt = (int)((n8 + 255) / 256);
    int ept = (E + P2B * 256 - 1) / (P2B * 256);   // 13 for E=1.6M (<= MAXEPT)

    // fused front: pass2 sorted-partition | cvt | w frags
    fused_front<<<P2B + ncvt + 24, 256, 0, stream>>>(
        x, xb, n8, ncvt, W1_l, W1_r, w1frag, W2_l, W2_r, w2frag,
        ei32, ei64, E, ept, nbuck, N, bucket_pos, ebuf);

    pass3_finalize<<<nbuck, 256, 0, stream>>>(ebuf, bucket_pos, nbuck, N,
                                              startcnt, csr);

    // merged: 16-node agg + in-block gemm1+gemm2 (barrier handoff only)
    int gblocks = (N + 15) / 16;   // 6250, exact
    agg16_gemm<<<gblocks, 1024, 0, stream>>>(xb, startcnt, csr,
                                             w1frag, w2frag, b1, b2,
                                             z2, out, N);

    // layer 2 agg (commuted, dual-node waves) + in-place epilogue on out
    int a64blocks = (N + 7) / 8;
    agg_mean64_bf_ep<<<a64blocks, 256, 0, stream>>>(z2, startcnt, csr, out, N);
}